// Round 1
// baseline (33.966 us; speedup 1.0000x reference)
//
#include <hip/hip_runtime.h>

#define GTCR_EPS 0.001f

// Kernel 1: one block per row. Compute log1p(lmbd * ||z_row||^2) -> ws[row].
__global__ __launch_bounds__(256) void gtcr_row_kernel(
    const float* __restrict__ z, float* __restrict__ row_out,
    float lmbd, int D) {
    const int row = blockIdx.x;
    const float4* zr = reinterpret_cast<const float4*>(z + (size_t)row * (size_t)D);
    const int n4 = D >> 2;  // 1024 float4 per row

    float s = 0.0f;
    // Coalesced: consecutive lanes read consecutive float4 (16B/lane).
    for (int i = threadIdx.x; i < n4; i += blockDim.x) {
        float4 v = zr[i];
        s = fmaf(v.x, v.x, s);
        s = fmaf(v.y, v.y, s);
        s = fmaf(v.z, v.z, s);
        s = fmaf(v.w, v.w, s);
    }

    // Wave-64 shuffle reduction.
    #pragma unroll
    for (int off = 32; off > 0; off >>= 1)
        s += __shfl_down(s, off, 64);

    __shared__ float wsum[4];
    const int lane = threadIdx.x & 63;
    const int wid  = threadIdx.x >> 6;
    if (lane == 0) wsum[wid] = s;
    __syncthreads();
    if (threadIdx.x == 0) {
        float t = wsum[0] + wsum[1] + wsum[2] + wsum[3];
        row_out[row] = log1pf(lmbd * t);
    }
}

// Kernel 2: single block reduces B row values -> -0.5 * mean.
__global__ __launch_bounds__(256) void gtcr_final_kernel(
    const float* __restrict__ row_vals, float* __restrict__ out, int B) {
    float s = 0.0f;
    for (int i = threadIdx.x; i < B; i += 256)
        s += row_vals[i];

    #pragma unroll
    for (int off = 32; off > 0; off >>= 1)
        s += __shfl_down(s, off, 64);

    __shared__ float wsum[4];
    const int lane = threadIdx.x & 63;
    const int wid  = threadIdx.x >> 6;
    if (lane == 0) wsum[wid] = s;
    __syncthreads();
    if (threadIdx.x == 0) {
        float t = wsum[0] + wsum[1] + wsum[2] + wsum[3];
        out[0] = -0.5f * (t / (float)B);
    }
}

extern "C" void kernel_launch(void* const* d_in, const int* in_sizes, int n_in,
                              void* d_out, int out_size, void* d_ws, size_t ws_size,
                              hipStream_t stream) {
    const float* z = (const float*)d_in[0];
    float* out = (float*)d_out;
    float* row_vals = (float*)d_ws;  // B floats of scratch

    const int D = 4096;
    const int B = in_sizes[0] / D;  // 8192
    const float lmbd = (float)D * ((float)B * GTCR_EPS);  // 33554.432

    gtcr_row_kernel<<<B, 256, 0, stream>>>(z, row_vals, lmbd, D);
    gtcr_final_kernel<<<1, 256, 0, stream>>>(row_vals, out, B);
}

// Round 2
// 29.002 us; speedup vs baseline: 1.1712x; 1.1712x over previous
//
#include <hip/hip_runtime.h>

#define GTCR_EPS 0.001f
#define GTCR_D 4096

// Kernel 1: one block per row (D=4096 fixed). 256 threads x 4 float4 loads,
// all issued before use (MLP=4/thread). log1p(lmbd * ||z_row||^2) -> row_out.
__global__ __launch_bounds__(256) void gtcr_row_kernel(
    const float* __restrict__ z, float* __restrict__ row_out, float lmbd) {
    const int row = blockIdx.x;
    const float4* zr = reinterpret_cast<const float4*>(z) + (size_t)row * (GTCR_D / 4);
    const int t = threadIdx.x;

    // 4 independent 16B loads, coalesced (consecutive lanes -> consecutive float4).
    float4 v0 = zr[t];
    float4 v1 = zr[t + 256];
    float4 v2 = zr[t + 512];
    float4 v3 = zr[t + 768];

    float s0 = fmaf(v0.x, v0.x, fmaf(v0.y, v0.y, fmaf(v0.z, v0.z, v0.w * v0.w)));
    float s1 = fmaf(v1.x, v1.x, fmaf(v1.y, v1.y, fmaf(v1.z, v1.z, v1.w * v1.w)));
    float s2 = fmaf(v2.x, v2.x, fmaf(v2.y, v2.y, fmaf(v2.z, v2.z, v2.w * v2.w)));
    float s3 = fmaf(v3.x, v3.x, fmaf(v3.y, v3.y, fmaf(v3.z, v3.z, v3.w * v3.w)));
    float s = (s0 + s1) + (s2 + s3);

    // Wave-64 shuffle reduction.
    #pragma unroll
    for (int off = 32; off > 0; off >>= 1)
        s += __shfl_down(s, off, 64);

    __shared__ float wsum[4];
    const int lane = threadIdx.x & 63;
    const int wid  = threadIdx.x >> 6;
    if (lane == 0) wsum[wid] = s;
    __syncthreads();
    if (threadIdx.x == 0) {
        float t4 = (wsum[0] + wsum[1]) + (wsum[2] + wsum[3]);
        row_out[row] = log1pf(lmbd * t4);
    }
}

// Kernel 2: single block reduces B row values -> -0.5 * mean.
__global__ __launch_bounds__(256) void gtcr_final_kernel(
    const float* __restrict__ row_vals, float* __restrict__ out, int B) {
    const float4* rv4 = reinterpret_cast<const float4*>(row_vals);
    const int n4 = B >> 2;  // 2048
    float s = 0.0f;
    for (int i = threadIdx.x; i < n4; i += 256) {
        float4 v = rv4[i];
        s += (v.x + v.y) + (v.z + v.w);
    }

    #pragma unroll
    for (int off = 32; off > 0; off >>= 1)
        s += __shfl_down(s, off, 64);

    __shared__ float wsum[4];
    const int lane = threadIdx.x & 63;
    const int wid  = threadIdx.x >> 6;
    if (lane == 0) wsum[wid] = s;
    __syncthreads();
    if (threadIdx.x == 0) {
        float t = (wsum[0] + wsum[1]) + (wsum[2] + wsum[3]);
        out[0] = -0.5f * (t / (float)B);
    }
}

extern "C" void kernel_launch(void* const* d_in, const int* in_sizes, int n_in,
                              void* d_out, int out_size, void* d_ws, size_t ws_size,
                              hipStream_t stream) {
    const float* z = (const float*)d_in[0];
    float* out = (float*)d_out;
    float* row_vals = (float*)d_ws;  // B floats of scratch

    const int B = in_sizes[0] / GTCR_D;  // 8192
    const float lmbd = (float)GTCR_D * ((float)B * GTCR_EPS);  // 33554.432

    gtcr_row_kernel<<<B, 256, 0, stream>>>(z, row_vals, lmbd);
    gtcr_final_kernel<<<1, 256, 0, stream>>>(row_vals, out, B);
}